// Round 1
// 2306.362 us; speedup vs baseline: 1.3602x; 1.3602x over previous
//
#include <hip/hip_runtime.h>

#define VOCAB 32000
#define DIM   256
#define UN    512
#define TT    128
#define T1    126
#define NG    2048  // 4*UN
#define NBLK  256

typedef __attribute__((ext_vector_type(8))) __bf16 bf16x8;
typedef __attribute__((ext_vector_type(4))) float  f32x4;

__device__ __forceinline__ unsigned short f2bf(float f) {
  union { float f; unsigned u; } v; v.f = f;
  unsigned r = (v.u + 0x7fffu + ((v.u >> 16) & 1u)) >> 16;
  return (unsigned short)r;
}
__device__ __forceinline__ float f4_get(const float4& v, int j) {
  return j == 0 ? v.x : j == 1 ? v.y : j == 2 ? v.z : v.w;
}
__device__ __forceinline__ void async16(const void* g, void* l) {
  __builtin_amdgcn_global_load_lds((const __attribute__((address_space(1))) void*)g,
                                   (__attribute__((address_space(3))) void*)l, 16, 0, 0);
}

// ---------------- embedding gather ----------------------------------------
__global__ __launch_bounds__(256) void k_gather(const int* __restrict__ seqs,
                                                const float* __restrict__ embed,
                                                float* __restrict__ emb) {
  int idx = blockIdx.x * 256 + threadIdx.x;     // 16*128*64 float4 units
  int d4 = idx & 63, bt = idx >> 6;
  int tok = seqs[bt];
  ((float4*)emb)[idx] = ((const float4*)embed)[(size_t)tok * 64 + d4];
}

// ---------------- layer0 input projection Z0 = x@W0 + b0 ------------------
__global__ __launch_bounds__(256, 2) void k_zin(const float* __restrict__ emb,
    const float* __restrict__ fW0, const float* __restrict__ fb0,
    const float* __restrict__ bW0, const float* __restrict__ bb0,
    float* __restrict__ Z0) {
  __shared__ __align__(16) float xs[16 * 260];
  int bi = blockIdx.x;              // 2(jh) * 126 * 2(dir) = 504
  int jh  = bi & 1;
  int t   = (bi >> 1) % T1;
  int dir = (bi >> 1) / T1;
  int tim = dir ? (TT - 1) - t : t;
  const float* W    = dir ? bW0 : fW0;
  const float* bias = dir ? bb0 : fb0;
  int tid = threadIdx.x;
  #pragma unroll
  for (int i = 0; i < 4; ++i) {
    int fidx = i * 256 + tid;
    int b = fidx >> 6, k4 = fidx & 63;
    float4 v = ((const float4*)emb)[(size_t)(b * TT + tim) * 64 + k4];
    *(float4*)&xs[b * 260 + k4 * 4] = v;
  }
  __syncthreads();
  int j0 = jh * 1024 + tid;
  float acc[4][16];
  #pragma unroll
  for (int q = 0; q < 4; ++q) {
    float bv = bias[j0 + q * 256];
    #pragma unroll
    for (int b = 0; b < 16; ++b) acc[q][b] = bv;
  }
  #pragma unroll 2
  for (int k = 0; k < DIM; k += 4) {
    float4 xv[16];
    #pragma unroll
    for (int b = 0; b < 16; ++b) xv[b] = *(const float4*)&xs[b * 260 + k];
    #pragma unroll
    for (int kk = 0; kk < 4; ++kk) {
      float w[4];
      #pragma unroll
      for (int q = 0; q < 4; ++q) w[q] = W[(size_t)(k + kk) * NG + j0 + q * 256];
      #pragma unroll
      for (int q = 0; q < 4; ++q)
        #pragma unroll
        for (int b = 0; b < 16; ++b)
          acc[q][b] += f4_get(xv[b], kk) * w[q];
    }
  }
  float* out = Z0 + ((size_t)(dir * T1 + t) * 16) * NG;
  #pragma unroll
  for (int q = 0; q < 4; ++q)
    #pragma unroll
    for (int b = 0; b < 16; ++b)
      out[(size_t)b * NG + j0 + q * 256] = acc[q][b];
}

// ---------------- Wp cast+transpose: Bt[n][k] = bf16(Wp[k][n]) -------------
__global__ __launch_bounds__(256) void k_cast_wp(const float* __restrict__ Wp,
                                                 unsigned short* __restrict__ Bt) {
  __shared__ float tile[32][33];
  int bi = blockIdx.x;               // 32 ktiles * 1000 ntiles
  int kt = bi & 31, nt = bi >> 5;
  int k0 = kt * 32, n0 = nt * 32;
  int tid = threadIdx.x;
  int nl = tid & 31, kl = tid >> 5;
  #pragma unroll
  for (int i = 0; i < 4; ++i) {
    int k = kl + i * 8;
    tile[k][nl] = Wp[(size_t)(k0 + k) * VOCAB + n0 + nl];
  }
  __syncthreads();
  int kl2 = tid & 31, nl2 = tid >> 5;
  #pragma unroll
  for (int i = 0; i < 4; ++i) {
    int n = nl2 + i * 8;
    Bt[(size_t)(n0 + n) * 1024 + k0 + kl2] = f2bf(tile[kl2][n]);
  }
}

// ---------------- zero A pad rows 2016..2047 -------------------------------
__global__ __launch_bounds__(256) void k_padA(unsigned short* __restrict__ A) {
  int idx = blockIdx.x * 256 + threadIdx.x;     // 4096 uint4
  ((uint4*)(A + (size_t)2016 * 1024))[idx] = make_uint4(0u, 0u, 0u, 0u);
}

// ---------------- recurrence ------------------------------------------------
// Producer-consumer counter sync replaces the full grid barrier.
// 4 groups = (layer,dir), 64 blocks each. After finishing time-step t a block
// bumps one of its group's 8 sub-counters (128 B apart, relaxed agent atomic).
// Dependencies:  L0-d step t needs cnt_L0d >= 64*t        (reads h0[t-1])
//                L1-d step t needs cnt_L0d >= 64*(t+1)    (reads h0[t])
//                             and  cnt_L1d >= 64*t        (reads h1[t-1])
// h values are published with agent-scope write-through stores (sc1 -> MALL,
// the memory-side coherent cache); vmcnt drain before the signal makes them
// globally visible WITHOUT buffer_wbl2/buffer_inv whole-L2 fences.
// Readers use plain cached loads: every h address is time-indexed and
// first-touched only after its producer count is observed, so no cache can
// hold a stale copy, and the XCD L2 amortizes the 32KB broadcast across the
// 32 blocks of each XCD.

__device__ __forceinline__ void waitcnt_group(const int* g, int target) {
  if (threadIdx.x == 0) {
    for (;;) {
      int s = 0;
      #pragma unroll
      for (int i = 0; i < 8; ++i)
        s += __hip_atomic_load((const int*)(g + i * 32), __ATOMIC_RELAXED,
                               __HIP_MEMORY_SCOPE_AGENT);
      if (s >= target) break;
      __builtin_amdgcn_s_sleep(1);
    }
  }
  __syncthreads();
}

__device__ __forceinline__ void waitcnt_group2(const int* g1, int t1,
                                               const int* g2, int t2) {
  if (threadIdx.x == 0) {
    for (;;) {
      int s1 = 0, s2 = 0;
      #pragma unroll
      for (int i = 0; i < 8; ++i) {
        s1 += __hip_atomic_load((const int*)(g1 + i * 32), __ATOMIC_RELAXED,
                                __HIP_MEMORY_SCOPE_AGENT);
        s2 += __hip_atomic_load((const int*)(g2 + i * 32), __ATOMIC_RELAXED,
                                __HIP_MEMORY_SCOPE_AGENT);
      }
      if (s1 >= t1 && s2 >= t2) break;
      __builtin_amdgcn_s_sleep(1);
    }
  }
  __syncthreads();
}

__device__ __forceinline__ void signal_group(int* sub) {
  __builtin_amdgcn_s_waitcnt(0);     // belt+suspenders: drain this wave's vmem
  __syncthreads();                   // all waves' h stores complete before add
  if (threadIdx.x == 0)
    __hip_atomic_fetch_add(sub, 1, __ATOMIC_RELAXED, __HIP_MEMORY_SCOPE_AGENT);
}

// xs: per-b 512 floats as 32 groups of 16 padded to 20 (bank-conflict-free).
__device__ __forceinline__ void stage1(float* xs, const float* __restrict__ src) {
  const int tid = threadIdx.x;
  #pragma unroll
  for (int i = 0; i < 8; ++i) {
    const int fidx = i * 256 + tid;
    const int b = fidx >> 7, k = (fidx & 127) * 4;
    const float4 v = src ? *(const float4*)&src[(size_t)b * 512 + k]
                         : make_float4(0.f, 0.f, 0.f, 0.f);
    *(float4*)&xs[b * 640 + (k >> 4) * 20 + (k & 15)] = v;
  }
}

// issue both load sets before either LDS write so global latency overlaps
__device__ __forceinline__ void stage2(float* xsA, const float* __restrict__ srcA,
                                       float* xsB, const float* __restrict__ srcB) {
  const int tid = threadIdx.x;
  float4 va[8], vb[8];
  #pragma unroll
  for (int i = 0; i < 8; ++i) {
    const int fidx = i * 256 + tid;
    const int b = fidx >> 7, k = (fidx & 127) * 4;
    va[i] = *(const float4*)&srcA[(size_t)b * 512 + k];
    vb[i] = srcB ? *(const float4*)&srcB[(size_t)b * 512 + k]
                 : make_float4(0.f, 0.f, 0.f, 0.f);
  }
  #pragma unroll
  for (int i = 0; i < 8; ++i) {
    const int fidx = i * 256 + tid;
    const int b = fidx >> 7, k = (fidx & 127) * 4;
    *(float4*)&xsA[b * 640 + (k >> 4) * 20 + (k & 15)] = va[i];
    *(float4*)&xsB[b * 640 + (k >> 4) * 20 + (k & 15)] = vb[i];
  }
}

__device__ __forceinline__ void phase_acc(const float* xs, const float (&u)[4][16],
                                          float (&acc)[4][16], int kp) {
  const float* xb = xs + kp * 20;
  #pragma unroll
  for (int kk4 = 0; kk4 < 4; ++kk4) {
    float4 xv[16];
    #pragma unroll
    for (int b = 0; b < 16; ++b) xv[b] = *(const float4*)&xb[b * 640 + kk4 * 4];
    #pragma unroll
    for (int j = 0; j < 4; ++j)
      #pragma unroll
      for (int g = 0; g < 4; ++g) {
        float uv = u[g][kk4 * 4 + j];
        #pragma unroll
        for (int b = 0; b < 16; ++b) acc[g][b] += f4_get(xv[b], j) * uv;
      }
  }
}

template <int LAYER>
__device__ void recur_path(const int* __restrict__ seqs,
                           const float* __restrict__ Z0,
                           const float* __restrict__ P1,   // L0: U0 ; L1: W1
                           const float* __restrict__ P2,   // L1: U1
                           const float* __restrict__ b1,
                           float* __restrict__ H0,
                           float* __restrict__ h1,         // [126][2][16][512]
                           unsigned short* __restrict__ A,
                           int* cnt_own, int* sub_own, int* cnt_l0,
                           float* xsA, float* xsB, float* red,
                           int dir, int u0)
{
  const int tid = threadIdx.x;
  const int kp = tid >> 3;
  const int unit = u0 + (tid & 7);
  float u1r[4][16], u2r[4][16];
  #pragma unroll
  for (int g = 0; g < 4; ++g)
    #pragma unroll
    for (int kk = 0; kk < 16; ++kk) {
      const int col = g * UN + unit;
      u1r[g][kk] = P1[(size_t)(kp * 16 + kk) * NG + col];
      if (LAYER) u2r[g][kk] = P2[(size_t)(kp * 16 + kk) * NG + col];
    }
  const int cu = tid & 7, cb = tid >> 3;   // updater-thread role (tid<128)
  const int un = u0 + cu;
  float b1r[4] = {0.f, 0.f, 0.f, 0.f};
  if (LAYER && tid < 128) {
    #pragma unroll
    for (int g = 0; g < 4; ++g) b1r[g] = b1[g * UN + un];
  }
  float hst = 0.f, cstate = 0.f;           // updater-thread cell state

  for (int t = 0; t < 126; ++t) {
    // prefetch mask + Z0 slice above the poll so latency hides under it
    float zp[4] = {0.f, 0.f, 0.f, 0.f};
    bool m = false;
    if (tid < 128) {
      const int tim = dir ? (TT - 1) - t : t;
      m = seqs[cb * TT + tim] != 0;
      if (LAYER == 0) {
        const float* zr = Z0 + (((size_t)dir * T1 + t) * 16 + cb) * NG;
        #pragma unroll
        for (int g = 0; g < 4; ++g) zp[g] = zr[g * UN + un];
      }
    }
    if (LAYER == 0) {
      if (t == 0) {
        stage1(xsA, nullptr);
      } else {
        waitcnt_group(cnt_own, 64 * t);
        stage1(xsA, H0 + ((size_t)(dir * T1 + (t - 1)) * 16) * UN);
      }
    } else {
      const float* srcA = H0 + ((size_t)(dir * T1 + t) * 16) * UN;
      if (t == 0) {
        waitcnt_group(cnt_l0, 64);
        stage2(xsA, srcA, xsB, nullptr);
      } else {
        waitcnt_group2(cnt_l0, 64 * (t + 1), cnt_own, 64 * t);
        stage2(xsA, srcA, xsB, h1 + ((size_t)((t - 1) * 2 + dir) * 16) * UN);
      }
    }
    __syncthreads();

    float acc[4][16];
    #pragma unroll
    for (int g = 0; g < 4; ++g)
      #pragma unroll
      for (int b = 0; b < 16; ++b) acc[g][b] = 0.f;
    phase_acc(xsA, u1r, acc, kp);
    if (LAYER) phase_acc(xsB, u2r, acc, kp);

    #pragma unroll
    for (int g = 0; g < 4; ++g)
      #pragma unroll
      for (int b = 0; b < 16; ++b) {
        float v = acc[g][b];
        v += __shfl_xor(v, 8);
        v += __shfl_xor(v, 16);
        v += __shfl_xor(v, 32);
        acc[g][b] = v;
      }
    const int lane = tid & 63, wv = tid >> 6;
    if (lane < 8) {
      #pragma unroll
      for (int g = 0; g < 4; ++g)
        #pragma unroll
        for (int b = 0; b < 16; ++b)
          red[((wv * 8 + lane) * 4 + g) * 17 + b] = acc[g][b];
    }
    __syncthreads();

    if (tid < 128) {
      float z[4];
      #pragma unroll
      for (int g = 0; g < 4; ++g) {
        float v = red[(cu * 4 + g) * 17 + cb];
        #pragma unroll
        for (int w = 1; w < 4; ++w) v += red[((w * 8 + cu) * 4 + g) * 17 + cb];
        z[g] = v + (LAYER ? b1r[g] : zp[g]);
      }
      const float si = 1.f / (1.f + expf(-z[0]));
      const float sf = 1.f / (1.f + expf(-z[1]));
      const float tg = tanhf(z[2]);
      const float so = 1.f / (1.f + expf(-z[3]));
      const float cn = sf * cstate + si * tg;
      const float hn = so * tanhf(cn);
      const float hsel = m ? hn : hst;
      const float csel = m ? cn : cstate;
      cstate = csel; hst = hsel;
      if (LAYER == 0) {
        // agent-scope write-through: lands at MALL (coherent) before signal
        __hip_atomic_store(&H0[(((size_t)dir * T1 + t) * 16 + cb) * UN + un],
                           hsel, __ATOMIC_RELAXED, __HIP_MEMORY_SCOPE_AGENT);
      } else {
        __hip_atomic_store(&h1[(((size_t)t * 2 + dir) * 16 + cb) * UN + un],
                           hsel, __ATOMIC_RELAXED, __HIP_MEMORY_SCOPE_AGENT);
        const int row = dir ? (125 - t) : t;
        A[((size_t)cb * T1 + row) * 1024 + dir * UN + un] = f2bf(hsel); // post-kernel consumer
      }
    }
    signal_group(sub_own);
  }
}

__global__ __launch_bounds__(256, 1) void k_recur(
    const int* __restrict__ seqs, const float* __restrict__ Z0,
    const float* __restrict__ fU0, const float* __restrict__ bU0,
    const float* __restrict__ fW1, const float* __restrict__ fU1, const float* __restrict__ fb1,
    const float* __restrict__ bW1, const float* __restrict__ bU1, const float* __restrict__ bb1,
    float* __restrict__ H0, float* __restrict__ h1, unsigned short* __restrict__ A,
    int* __restrict__ bar)
{
  __shared__ __align__(16) float xs[2][16 * 640];   // 80 KB (dual input buffers)
  __shared__ float red[32 * 4 * 17];                // 8.5 KB
  const int bi = blockIdx.x;
  const int dir = (bi >> 6) & 1;
  const int u0 = (bi & 63) * 8;
  const int gid = bi >> 6;                 // 0:L0f 1:L0b 2:L1f 3:L1b
  int* cnt_own = bar + gid * 256;          // 8 sub-counters, 128 B apart
  int* sub_own = cnt_own + (bi & 7) * 32;  // bi&7 spreads subs across XCDs
  int* cnt_l0  = bar + dir * 256;
  if ((bi >> 7) == 0)
    recur_path<0>(seqs, Z0, dir ? bU0 : fU0, nullptr, nullptr,
                  H0, h1, A, cnt_own, sub_own, cnt_l0, xs[0], xs[1], red, dir, u0);
  else
    recur_path<1>(seqs, Z0, dir ? bW1 : fW1, dir ? bU1 : fU1, dir ? bb1 : fb1,
                  H0, h1, A, cnt_own, sub_own, cnt_l0, xs[0], xs[1], red, dir, u0);
}

// ---------------- projection: out[2016,32000] = A@Bt^T + bp (bf16 MFMA) ----
__global__ __launch_bounds__(256, 2) void k_proj(
    const unsigned short* __restrict__ Abf, const unsigned short* __restrict__ Bt,
    const float* __restrict__ bp, float* __restrict__ out)
{
  __shared__ unsigned short As[128 * 32];
  __shared__ unsigned short Bs[128 * 32];
  int bi = blockIdx.x;               // 16 mtiles (fast) x 250 ntiles
  int mt = bi & 15, nt = bi >> 4;
  int m0 = mt * 128, n0 = nt * 128;
  int tid = threadIdx.x;
  int wv = tid >> 6, lane = tid & 63;
  int wm = wv & 1, wn = wv >> 1;
  f32x4 acc[4][4] = {};
  for (int kt = 0; kt < 32; ++kt) {
    int r0 = wv * 32;
    #pragma unroll
    for (int i = 0; i < 2; ++i) {
      int row = r0 + i * 16 + (lane >> 2);
      const unsigned short* ga = Abf + (size_t)(m0 + row) * 1024 + kt * 32 + (lane & 3) * 8;
      async16(ga, As + (r0 + i * 16) * 32);
      const unsigned short* gb = Bt + (size_t)(n0 + row) * 1024 + kt * 32 + (lane & 3) * 8;
      async16(gb, Bs + (r0 + i * 16) * 32);
    }
    __syncthreads();
    bf16x8 af[4], bf[4];
    #pragma unroll
    for (int i = 0; i < 4; ++i) {
      int m = wm * 64 + i * 16 + (lane & 15);
      af[i] = *(const bf16x8*)&As[m * 32 + (lane >> 4) * 8];
      int n = wn * 64 + i * 16 + (lane & 15);
      bf[i] = *(const bf16x8*)&Bs[n * 32 + (lane >> 4) * 8];
    }
    #pragma unroll
    for (int i = 0; i < 4; ++i)
      #pragma unroll
      for (int j = 0; j < 4; ++j)
        acc[i][j] = __builtin_amdgcn_mfma_f32_16x16x32_bf16(af[i], bf[j], acc[i][j], 0, 0, 0);
    __syncthreads();
  }
  #pragma unroll
  for (int j = 0; j < 4; ++j) {
    int col = n0 + wn * 64 + j * 16 + (lane & 15);
    float bv = bp[col];
    #pragma unroll
    for (int i = 0; i < 4; ++i) {
      int rbase = m0 + wm * 64 + i * 16 + (lane >> 4) * 4;
      #pragma unroll
      for (int r = 0; r < 4; ++r) {
        int row = rbase + r;
        if (row < 2016) out[(size_t)row * VOCAB + col] = acc[i][j][r] + bv;
      }
    }
  }
}

// ---------------- host ------------------------------------------------------
extern "C" void kernel_launch(void* const* d_in, const int* in_sizes, int n_in,
                              void* d_out, int out_size, void* d_ws, size_t ws_size,
                              hipStream_t stream)
{
  const int*   seqs  = (const int*)  d_in[0];
  const float* embed = (const float*)d_in[1];
  const float* fW0 = (const float*)d_in[2];
  const float* fU0 = (const float*)d_in[3];
  const float* fb0 = (const float*)d_in[4];
  const float* fW1 = (const float*)d_in[5];
  const float* fU1 = (const float*)d_in[6];
  const float* fb1 = (const float*)d_in[7];
  const float* bW0 = (const float*)d_in[8];
  const float* bU0 = (const float*)d_in[9];
  const float* bb0 = (const float*)d_in[10];
  const float* bW1 = (const float*)d_in[11];
  const float* bU1 = (const float*)d_in[12];
  const float* bb1 = (const float*)d_in[13];
  const float* Wp  = (const float*)d_in[14];
  const float* bp  = (const float*)d_in[15];
  float* out = (float*)d_out;

  char* ws = (char*)d_ws;
  float* emb   = (float*)(ws);                           //  2,097,152 B
  float* Z0    = (float*)(ws + 2097152);                 // 33,030,144 B
  float* H0    = (float*)(ws + 35127296);                //  8,257,536 B
  float* h1    = (float*)(ws + 43384832);                //  8,257,536 B
  unsigned short* A  = (unsigned short*)(ws + 51642368); //  4,194,304 B
  unsigned short* Bt = (unsigned short*)(ws + 55836672); // 65,536,000 B
  // counters overlap the emb region (emb is dead after k_zin; memset is
  // stream-ordered after k_zin below). 4 groups x 8 subs x 128 B = 4 KB.
  int* bar = (int*)(ws + 1048576);
  // total ws use: 121,372,672 bytes

  hipLaunchKernelGGL(k_gather, dim3(512), dim3(256), 0, stream, seqs, embed, emb);
  hipLaunchKernelGGL(k_zin, dim3(504), dim3(256), 0, stream, emb, fW0, fb0, bW0, bb0, Z0);
  hipLaunchKernelGGL(k_cast_wp, dim3(32000), dim3(256), 0, stream, Wp, Bt);
  hipLaunchKernelGGL(k_padA, dim3(16), dim3(256), 0, stream, A);
  hipMemsetAsync(bar, 0, 4096, stream);   // after k_zin: emb region now dead

  void* rargs[] = {(void*)&seqs, (void*)&Z0, (void*)&fU0, (void*)&bU0,
                   (void*)&fW1, (void*)&fU1, (void*)&fb1,
                   (void*)&bW1, (void*)&bU1, (void*)&bb1,
                   (void*)&H0, (void*)&h1, (void*)&A, (void*)&bar};
  hipError_t ce = hipLaunchCooperativeKernel((void*)k_recur, dim3(NBLK), dim3(256),
                                             rargs, 0, stream);
  if (ce != hipSuccess) {
    (void)hipGetLastError();   // clear sticky error; fall back to plain launch
    hipLaunchKernelGGL(k_recur, dim3(NBLK), dim3(256), 0, stream,
                       seqs, Z0, fU0, bU0, fW1, fU1, fb1, bW1, bU1, bb1,
                       H0, h1, A, bar);
  }

  hipLaunchKernelGGL(k_proj, dim3(4000), dim3(256), 0, stream, A, Bt, bp, out);
}

// Round 2
// 2088.307 us; speedup vs baseline: 1.5023x; 1.1044x over previous
//
#include <hip/hip_runtime.h>

#define VOCAB 32000
#define DIM   256
#define UN    512
#define TT    128
#define T1    126
#define NG    2048  // 4*UN
#define NBLK  256

typedef __attribute__((ext_vector_type(8))) __bf16 bf16x8;
typedef __attribute__((ext_vector_type(4))) float  f32x4;

__device__ __forceinline__ unsigned short f2bf(float f) {
  union { float f; unsigned u; } v; v.f = f;
  unsigned r = (v.u + 0x7fffu + ((v.u >> 16) & 1u)) >> 16;
  return (unsigned short)r;
}
__device__ __forceinline__ float f4_get(const float4& v, int j) {
  return j == 0 ? v.x : j == 1 ? v.y : j == 2 ? v.z : v.w;
}
__device__ __forceinline__ void async16(const void* g, void* l) {
  __builtin_amdgcn_global_load_lds((const __attribute__((address_space(1))) void*)g,
                                   (__attribute__((address_space(3))) void*)l, 16, 0, 0);
}

// ---------------- embedding gather ----------------------------------------
__global__ __launch_bounds__(256) void k_gather(const int* __restrict__ seqs,
                                                const float* __restrict__ embed,
                                                float* __restrict__ emb) {
  int idx = blockIdx.x * 256 + threadIdx.x;     // 16*128*64 float4 units
  int d4 = idx & 63, bt = idx >> 6;
  int tok = seqs[bt];
  ((float4*)emb)[idx] = ((const float4*)embed)[(size_t)tok * 64 + d4];
}

// ---------------- layer0 input projection Z0 = x@W0 + b0 ------------------
__global__ __launch_bounds__(256, 2) void k_zin(const float* __restrict__ emb,
    const float* __restrict__ fW0, const float* __restrict__ fb0,
    const float* __restrict__ bW0, const float* __restrict__ bb0,
    float* __restrict__ Z0) {
  __shared__ __align__(16) float xs[16 * 260];
  int bi = blockIdx.x;              // 2(jh) * 126 * 2(dir) = 504
  int jh  = bi & 1;
  int t   = (bi >> 1) % T1;
  int dir = (bi >> 1) / T1;
  int tim = dir ? (TT - 1) - t : t;
  const float* W    = dir ? bW0 : fW0;
  const float* bias = dir ? bb0 : fb0;
  int tid = threadIdx.x;
  #pragma unroll
  for (int i = 0; i < 4; ++i) {
    int fidx = i * 256 + tid;
    int b = fidx >> 6, k4 = fidx & 63;
    float4 v = ((const float4*)emb)[(size_t)(b * TT + tim) * 64 + k4];
    *(float4*)&xs[b * 260 + k4 * 4] = v;
  }
  __syncthreads();
  int j0 = jh * 1024 + tid;
  float acc[4][16];
  #pragma unroll
  for (int q = 0; q < 4; ++q) {
    float bv = bias[j0 + q * 256];
    #pragma unroll
    for (int b = 0; b < 16; ++b) acc[q][b] = bv;
  }
  #pragma unroll 2
  for (int k = 0; k < DIM; k += 4) {
    float4 xv[16];
    #pragma unroll
    for (int b = 0; b < 16; ++b) xv[b] = *(const float4*)&xs[b * 260 + k];
    #pragma unroll
    for (int kk = 0; kk < 4; ++kk) {
      float w[4];
      #pragma unroll
      for (int q = 0; q < 4; ++q) w[q] = W[(size_t)(k + kk) * NG + j0 + q * 256];
      #pragma unroll
      for (int q = 0; q < 4; ++q)
        #pragma unroll
        for (int b = 0; b < 16; ++b)
          acc[q][b] += f4_get(xv[b], kk) * w[q];
    }
  }
  float* out = Z0 + ((size_t)(dir * T1 + t) * 16) * NG;
  #pragma unroll
  for (int q = 0; q < 4; ++q)
    #pragma unroll
    for (int b = 0; b < 16; ++b)
      out[(size_t)b * NG + j0 + q * 256] = acc[q][b];
}

// ---------------- Wp cast+transpose: Bt[n][k] = bf16(Wp[k][n]) -------------
__global__ __launch_bounds__(256) void k_cast_wp(const float* __restrict__ Wp,
                                                 unsigned short* __restrict__ Bt) {
  __shared__ float tile[32][33];
  int bi = blockIdx.x;               // 32 ktiles * 1000 ntiles
  int kt = bi & 31, nt = bi >> 5;
  int k0 = kt * 32, n0 = nt * 32;
  int tid = threadIdx.x;
  int nl = tid & 31, kl = tid >> 5;
  #pragma unroll
  for (int i = 0; i < 4; ++i) {
    int k = kl + i * 8;
    tile[k][nl] = Wp[(size_t)(k0 + k) * VOCAB + n0 + nl];
  }
  __syncthreads();
  int kl2 = tid & 31, nl2 = tid >> 5;
  #pragma unroll
  for (int i = 0; i < 4; ++i) {
    int n = nl2 + i * 8;
    Bt[(size_t)(n0 + n) * 1024 + k0 + kl2] = f2bf(tile[kl2][n]);
  }
}

// ---------------- zero A pad rows 2016..2047 -------------------------------
__global__ __launch_bounds__(256) void k_padA(unsigned short* __restrict__ A) {
  int idx = blockIdx.x * 256 + threadIdx.x;     // 4096 uint4
  ((uint4*)(A + (size_t)2016 * 1024))[idx] = make_uint4(0u, 0u, 0u, 0u);
}

// ---------------- recurrence ------------------------------------------------
// Producer-consumer sync with EPOCH BROADCAST.
// Per group (layer,dir): 8 spread sub-counters (adds), 1 master, 8 replicated
// epoch lines. Block signal: add to sub[bi&7]; the last adder of a sub-line
// (old == 8*(s+1)-1) adds to master; the last master-adder publishes
// epoch = s+1 to all 8 epoch copies. Consumers poll ONE epoch line (sc1,
// 4 B) with s_sleep backoff -> ~50x less MALL poll traffic than summing 8
// lines from every waiting block, and single-load detection.
// Ordering is fence-free: h stores (agent-scope write-through, drained by
// vmcnt before the sub add) complete at the MALL before the sub add is
// issued; sub->master->epoch are each issued only after the previous op's
// return value arrives; consumers first-touch time-indexed h only after
// observing epoch, so no cache can hold a stale copy.
// Dependencies: L0-d step t: epoch_own >= t       (reads h0[t-1])
//               L1-d step t: epoch_l0  >= t+1     (reads h0[t])
//                            epoch_own >= t       (reads h1[t-1])

__device__ __forceinline__ void wait_epoch(const int* ep, int target) {
  if (threadIdx.x == 0) {
    while (__hip_atomic_load(ep, __ATOMIC_RELAXED, __HIP_MEMORY_SCOPE_AGENT) < target)
      __builtin_amdgcn_s_sleep(2);
  }
  __syncthreads();
}

__device__ __forceinline__ void signal_step(int* grp, int sub_idx, int s) {
  __builtin_amdgcn_s_waitcnt(0);     // this wave's h stores at coherence point
  __syncthreads();                   // all waves drained before the add
  if (threadIdx.x == 0) {
    int old = __hip_atomic_fetch_add(grp + sub_idx * 32, 1,
                                     __ATOMIC_RELAXED, __HIP_MEMORY_SCOPE_AGENT);
    if (old == 8 * (s + 1) - 1) {
      int mold = __hip_atomic_fetch_add(grp + 256, 1,
                                        __ATOMIC_RELAXED, __HIP_MEMORY_SCOPE_AGENT);
      if (mold == 8 * (s + 1) - 1) {
        #pragma unroll
        for (int i = 0; i < 8; ++i)
          __hip_atomic_store(grp + 512 + i * 32, s + 1,
                             __ATOMIC_RELAXED, __HIP_MEMORY_SCOPE_AGENT);
      }
    }
  }
}

// xs: per-b 512 floats as 32 groups of 16 padded to 20 (bank-conflict-free).
__device__ __forceinline__ void ldstage_regs(float4 (&v)[8], const float* __restrict__ src) {
  const int tid = threadIdx.x;
  #pragma unroll
  for (int i = 0; i < 8; ++i) {
    const int fidx = i * 256 + tid;
    const int b = fidx >> 7, k = (fidx & 127) * 4;
    v[i] = *(const float4*)&src[(size_t)b * 512 + k];
  }
}
__device__ __forceinline__ void ldswrite(float* xs, const float4 (&v)[8]) {
  const int tid = threadIdx.x;
  #pragma unroll
  for (int i = 0; i < 8; ++i) {
    const int fidx = i * 256 + tid;
    const int b = fidx >> 7, k = (fidx & 127) * 4;
    *(float4*)&xs[b * 640 + (k >> 4) * 20 + (k & 15)] = v[i];
  }
}

__device__ __forceinline__ void phase_acc(const float* xs, const float (&u)[4][16],
                                          float (&acc)[4][16], int kp) {
  const float* xb = xs + kp * 20;
  #pragma unroll
  for (int kk4 = 0; kk4 < 4; ++kk4) {
    float4 xv[16];
    #pragma unroll
    for (int b = 0; b < 16; ++b) xv[b] = *(const float4*)&xb[b * 640 + kk4 * 4];
    #pragma unroll
    for (int j = 0; j < 4; ++j)
      #pragma unroll
      for (int g = 0; g < 4; ++g) {
        float uv = u[g][kk4 * 4 + j];
        #pragma unroll
        for (int b = 0; b < 16; ++b) acc[g][b] += f4_get(xv[b], j) * uv;
      }
  }
}

template <int LAYER>
__device__ void recur_path(const int* __restrict__ seqs,
                           const float* __restrict__ Z0,
                           const float* __restrict__ P1,   // L0: U0 ; L1: W1
                           const float* __restrict__ P2,   // L1: U1
                           const float* __restrict__ b1,
                           float* __restrict__ H0,
                           float* __restrict__ h1,         // [126][2][16][512]
                           unsigned short* __restrict__ A,
                           int* grp_own, int sub_idx,
                           const int* ep_own, const int* ep_l0,
                           float* xsA, float* xsB, float* red,
                           int dir, int u0)
{
  const int tid = threadIdx.x;
  const int kp = tid >> 3;
  const int unit = u0 + (tid & 7);
  float u1r[4][16], u2r[4][16];
  #pragma unroll
  for (int g = 0; g < 4; ++g)
    #pragma unroll
    for (int kk = 0; kk < 16; ++kk) {
      const int col = g * UN + unit;
      u1r[g][kk] = P1[(size_t)(kp * 16 + kk) * NG + col];
      if (LAYER) u2r[g][kk] = P2[(size_t)(kp * 16 + kk) * NG + col];
    }
  const int cu = tid & 7, cb = tid >> 3;   // updater-thread role (tid<128)
  const int un = u0 + cu;
  float b1r[4] = {0.f, 0.f, 0.f, 0.f};
  if (LAYER && tid < 128) {
    #pragma unroll
    for (int g = 0; g < 4; ++g) b1r[g] = b1[g * UN + un];
  }
  float hst = 0.f, cstate = 0.f;           // updater-thread cell state

  for (int t = 0; t < 126; ++t) {
    // prefetch mask + Z0 slice above the waits so latency hides under them
    float zp[4] = {0.f, 0.f, 0.f, 0.f};
    bool m = false;
    if (tid < 128) {
      const int tim = dir ? (TT - 1) - t : t;
      m = seqs[cb * TT + tim] != 0;
      if (LAYER == 0) {
        const float* zr = Z0 + (((size_t)dir * T1 + t) * 16 + cb) * NG;
        #pragma unroll
        for (int g = 0; g < 4; ++g) zp[g] = zr[g * UN + un];
      }
    }
    if (LAYER == 0) {
      float4 va[8];
      if (t == 0) {
        #pragma unroll
        for (int i = 0; i < 8; ++i) va[i] = make_float4(0.f, 0.f, 0.f, 0.f);
      } else {
        wait_epoch(ep_own, t);
        ldstage_regs(va, H0 + ((size_t)(dir * T1 + (t - 1)) * 16) * UN);
      }
      ldswrite(xsA, va);
    } else {
      float4 va[8], vb[8];
      if (t >= 1) {
        wait_epoch(ep_own, t);                       // h1[t-1] ready
        ldstage_regs(vb, h1 + ((size_t)((t - 1) * 2 + dir) * 16) * UN);
      } else {
        #pragma unroll
        for (int i = 0; i < 8; ++i) vb[i] = make_float4(0.f, 0.f, 0.f, 0.f);
      }
      wait_epoch(ep_l0, t + 1);                      // h0[t] ready; vb drains here
      ldstage_regs(va, H0 + ((size_t)(dir * T1 + t) * 16) * UN);
      ldswrite(xsB, vb);                             // overlaps va in flight
      ldswrite(xsA, va);
    }
    __syncthreads();

    float acc[4][16];
    #pragma unroll
    for (int g = 0; g < 4; ++g)
      #pragma unroll
      for (int b = 0; b < 16; ++b) acc[g][b] = 0.f;
    phase_acc(xsA, u1r, acc, kp);
    if (LAYER) phase_acc(xsB, u2r, acc, kp);

    #pragma unroll
    for (int g = 0; g < 4; ++g)
      #pragma unroll
      for (int b = 0; b < 16; ++b) {
        float v = acc[g][b];
        v += __shfl_xor(v, 8);
        v += __shfl_xor(v, 16);
        v += __shfl_xor(v, 32);
        acc[g][b] = v;
      }
    const int lane = tid & 63, wv = tid >> 6;
    if (lane < 8) {
      #pragma unroll
      for (int g = 0; g < 4; ++g)
        #pragma unroll
        for (int b = 0; b < 16; ++b)
          red[((wv * 8 + lane) * 4 + g) * 17 + b] = acc[g][b];
    }
    __syncthreads();

    if (tid < 128) {
      float z[4];
      #pragma unroll
      for (int g = 0; g < 4; ++g) {
        float v = red[(cu * 4 + g) * 17 + cb];
        #pragma unroll
        for (int w = 1; w < 4; ++w) v += red[((w * 8 + cu) * 4 + g) * 17 + cb];
        z[g] = v + (LAYER ? b1r[g] : zp[g]);
      }
      const float si = 1.f / (1.f + expf(-z[0]));
      const float sf = 1.f / (1.f + expf(-z[1]));
      const float tg = tanhf(z[2]);
      const float so = 1.f / (1.f + expf(-z[3]));
      const float cn = sf * cstate + si * tg;
      const float hn = so * tanhf(cn);
      const float hsel = m ? hn : hst;
      const float csel = m ? cn : cstate;
      cstate = csel; hst = hsel;
      if (LAYER == 0) {
        // agent-scope write-through: lands at MALL (coherent) before signal
        __hip_atomic_store(&H0[(((size_t)dir * T1 + t) * 16 + cb) * UN + un],
                           hsel, __ATOMIC_RELAXED, __HIP_MEMORY_SCOPE_AGENT);
      } else {
        __hip_atomic_store(&h1[(((size_t)t * 2 + dir) * 16 + cb) * UN + un],
                           hsel, __ATOMIC_RELAXED, __HIP_MEMORY_SCOPE_AGENT);
        const int row = dir ? (125 - t) : t;
        A[((size_t)cb * T1 + row) * 1024 + dir * UN + un] = f2bf(hsel); // post-kernel consumer
      }
    }
    signal_step(grp_own, sub_idx, t);
  }
}

__global__ __launch_bounds__(256, 1) void k_recur(
    const int* __restrict__ seqs, const float* __restrict__ Z0,
    const float* __restrict__ fU0, const float* __restrict__ bU0,
    const float* __restrict__ fW1, const float* __restrict__ fU1, const float* __restrict__ fb1,
    const float* __restrict__ bW1, const float* __restrict__ bU1, const float* __restrict__ bb1,
    float* __restrict__ H0, float* __restrict__ h1, unsigned short* __restrict__ A,
    int* __restrict__ bar)
{
  __shared__ __align__(16) float xs[2][16 * 640];   // 80 KB (dual input buffers)
  __shared__ float red[32 * 4 * 17];                // 8.5 KB
  const int bi = blockIdx.x;
  const int dir = (bi >> 6) & 1;
  const int u0 = (bi & 63) * 8;
  const int gid = bi >> 6;                 // 0:L0f 1:L0b 2:L1f 3:L1b
  // per-group 4KB region: sub[8] @ +i*32, master @ +256, epoch[8] @ +512+i*32
  int* grp_own = bar + gid * 1024;
  const int* ep_own = grp_own + 512 + (bi & 7) * 32;
  const int* ep_l0  = bar + dir * 1024 + 512 + (bi & 7) * 32;
  if ((bi >> 7) == 0)
    recur_path<0>(seqs, Z0, dir ? bU0 : fU0, nullptr, nullptr,
                  H0, h1, A, grp_own, bi & 7, ep_own, ep_l0,
                  xs[0], xs[1], red, dir, u0);
  else
    recur_path<1>(seqs, Z0, dir ? bW1 : fW1, dir ? bU1 : fU1, dir ? bb1 : fb1,
                  H0, h1, A, grp_own, bi & 7, ep_own, ep_l0,
                  xs[0], xs[1], red, dir, u0);
}

// ---------------- projection: out[2016,32000] = A@Bt^T + bp (bf16 MFMA) ----
__global__ __launch_bounds__(256, 2) void k_proj(
    const unsigned short* __restrict__ Abf, const unsigned short* __restrict__ Bt,
    const float* __restrict__ bp, float* __restrict__ out)
{
  __shared__ unsigned short As[128 * 32];
  __shared__ unsigned short Bs[128 * 32];
  int bi = blockIdx.x;               // 16 mtiles (fast) x 250 ntiles
  int mt = bi & 15, nt = bi >> 4;
  int m0 = mt * 128, n0 = nt * 128;
  int tid = threadIdx.x;
  int wv = tid >> 6, lane = tid & 63;
  int wm = wv & 1, wn = wv >> 1;
  f32x4 acc[4][4] = {};
  for (int kt = 0; kt < 32; ++kt) {
    int r0 = wv * 32;
    #pragma unroll
    for (int i = 0; i < 2; ++i) {
      int row = r0 + i * 16 + (lane >> 2);
      const unsigned short* ga = Abf + (size_t)(m0 + row) * 1024 + kt * 32 + (lane & 3) * 8;
      async16(ga, As + (r0 + i * 16) * 32);
      const unsigned short* gb = Bt + (size_t)(n0 + row) * 1024 + kt * 32 + (lane & 3) * 8;
      async16(gb, Bs + (r0 + i * 16) * 32);
    }
    __syncthreads();
    bf16x8 af[4], bf[4];
    #pragma unroll
    for (int i = 0; i < 4; ++i) {
      int m = wm * 64 + i * 16 + (lane & 15);
      af[i] = *(const bf16x8*)&As[m * 32 + (lane >> 4) * 8];
      int n = wn * 64 + i * 16 + (lane & 15);
      bf[i] = *(const bf16x8*)&Bs[n * 32 + (lane >> 4) * 8];
    }
    #pragma unroll
    for (int i = 0; i < 4; ++i)
      #pragma unroll
      for (int j = 0; j < 4; ++j)
        acc[i][j] = __builtin_amdgcn_mfma_f32_16x16x32_bf16(af[i], bf[j], acc[i][j], 0, 0, 0);
    __syncthreads();
  }
  #pragma unroll
  for (int j = 0; j < 4; ++j) {
    int col = n0 + wn * 64 + j * 16 + (lane & 15);
    float bv = bp[col];
    #pragma unroll
    for (int i = 0; i < 4; ++i) {
      int rbase = m0 + wm * 64 + i * 16 + (lane >> 4) * 4;
      #pragma unroll
      for (int r = 0; r < 4; ++r) {
        int row = rbase + r;
        if (row < 2016) out[(size_t)row * VOCAB + col] = acc[i][j][r] + bv;
      }
    }
  }
}

// ---------------- host ------------------------------------------------------
extern "C" void kernel_launch(void* const* d_in, const int* in_sizes, int n_in,
                              void* d_out, int out_size, void* d_ws, size_t ws_size,
                              hipStream_t stream)
{
  const int*   seqs  = (const int*)  d_in[0];
  const float* embed = (const float*)d_in[1];
  const float* fW0 = (const float*)d_in[2];
  const float* fU0 = (const float*)d_in[3];
  const float* fb0 = (const float*)d_in[4];
  const float* fW1 = (const float*)d_in[5];
  const float* fU1 = (const float*)d_in[6];
  const float* fb1 = (const float*)d_in[7];
  const float* bW0 = (const float*)d_in[8];
  const float* bU0 = (const float*)d_in[9];
  const float* bb0 = (const float*)d_in[10];
  const float* bW1 = (const float*)d_in[11];
  const float* bU1 = (const float*)d_in[12];
  const float* bb1 = (const float*)d_in[13];
  const float* Wp  = (const float*)d_in[14];
  const float* bp  = (const float*)d_in[15];
  float* out = (float*)d_out;

  char* ws = (char*)d_ws;
  float* emb   = (float*)(ws);                           //  2,097,152 B
  float* Z0    = (float*)(ws + 2097152);                 // 33,030,144 B
  float* H0    = (float*)(ws + 35127296);                //  8,257,536 B
  float* h1    = (float*)(ws + 43384832);                //  8,257,536 B
  unsigned short* A  = (unsigned short*)(ws + 51642368); //  4,194,304 B
  unsigned short* Bt = (unsigned short*)(ws + 55836672); // 65,536,000 B
  // counters overlap the emb region (emb is dead after k_zin; memset is
  // stream-ordered after k_zin below). 4 groups x 4 KB = 16 KB.
  int* bar = (int*)(ws + 1048576);
  // total ws use: 121,372,672 bytes

  hipLaunchKernelGGL(k_gather, dim3(512), dim3(256), 0, stream, seqs, embed, emb);
  hipLaunchKernelGGL(k_zin, dim3(504), dim3(256), 0, stream, emb, fW0, fb0, bW0, bb0, Z0);
  hipLaunchKernelGGL(k_cast_wp, dim3(32000), dim3(256), 0, stream, Wp, Bt);
  hipLaunchKernelGGL(k_padA, dim3(16), dim3(256), 0, stream, A);
  hipMemsetAsync(bar, 0, 16384, stream);   // after k_zin: emb region now dead

  void* rargs[] = {(void*)&seqs, (void*)&Z0, (void*)&fU0, (void*)&bU0,
                   (void*)&fW1, (void*)&fU1, (void*)&fb1,
                   (void*)&bW1, (void*)&bU1, (void*)&bb1,
                   (void*)&H0, (void*)&h1, (void*)&A, (void*)&bar};
  hipError_t ce = hipLaunchCooperativeKernel((void*)k_recur, dim3(NBLK), dim3(256),
                                             rargs, 0, stream);
  if (ce != hipSuccess) {
    (void)hipGetLastError();   // clear sticky error; fall back to plain launch
    hipLaunchKernelGGL(k_recur, dim3(NBLK), dim3(256), 0, stream,
                       seqs, Z0, fU0, bU0, fW1, fU1, fb1, bW1, bU1, bb1,
                       H0, h1, A, bar);
  }

  hipLaunchKernelGGL(k_proj, dim3(4000), dim3(256), 0, stream, A, Bt, bp, out);
}